// Round 5
// baseline (329.430 us; speedup 1.0000x reference)
//
#include <hip/hip_runtime.h>
#include <math.h>

#define NS 512
#define NF 40
#define ROWS_OUT 513
#define DTC (1.0f / 512.0f)
#define PLANE 520   // floats per component plane (512 + 8 pad)

// ws layout (floats):
//   [0..511]      w[m]
//   [512..1023]   cumw2[t]
//   [1024..1343]  per-forward constants, 8 per n:
//       0..2: cC = vol_scale*L[n]   3: q = nu*rho/vol_scale
//       4: cA3 = nu*sqrt(1-rho^2)   5: ca = 0.5*nu^2*DT
//       6: cm0 = mu0*DT             7: F0[n]

__global__ __launch_bounds__(512) void precomp_kernel(
    const float* __restrict__ F0, const float* __restrict__ alphas,
    const float* __restrict__ rhos, const float* __restrict__ nus,
    const float* __restrict__ tau, const float* __restrict__ L,
    const float* __restrict__ Lam, float* __restrict__ ws)
{
    __shared__ double sc[NS];
    __shared__ float omega0[NF];
    __shared__ float vs_s[NF];
    int tid = threadIdx.x;

    double m = (double)tid;
    double dt_alpha = pow(512.0, 0.4);          // DT^ALPHA = 512^0.4
    const double gamma06 = 1.4891922488128171;  // Gamma(0.6)
    double wv = (pow(m + 1.0, 0.6) - pow(m, 0.6)) * (1.0 / 0.6) * dt_alpha / gamma06;
    ws[tid] = (float)wv;
    sc[tid] = wv * wv;

    if (tid < NF) {
        float f0 = F0[tid];
        float vs = alphas[tid] * sqrtf(fabsf(f0 + 0.02f));
        vs_s[tid] = vs;
        omega0[tid] = tau[tid] * vs / (1.0f + tau[tid] * f0);
    }
    __syncthreads();

    for (int off = 1; off < NS; off <<= 1) {
        double u = (tid >= off) ? sc[tid - off] : 0.0;
        double v = sc[tid];
        __syncthreads();
        sc[tid] = v + u;
        __syncthreads();
    }
    ws[NS + tid] = (float)sc[tid];

    if (tid < NF) {
        int n = tid;
        float s = 0.0f;
        for (int j = 0; j < NF; ++j) s += Lam[n * NF + j] * omega0[j];
        float vs = vs_s[n];
        float mu0 = -vs * s;
        float rho = rhos[n], nu = nus[n];
        float* c = ws + 1024 + n * 8;
        c[0] = vs * L[n * 3 + 0];
        c[1] = vs * L[n * 3 + 1];
        c[2] = vs * L[n * 3 + 2];
        c[3] = nu * rho / fmaxf(vs, 1e-30f);
        c[4] = nu * sqrtf(fmaxf(1.0f - rho * rho, 0.0f));
        c[5] = 0.5f * nu * nu * DTC;
        c[6] = mu0 * DTC;
        c[7] = F0[n];
    }
}

// ---- wave64 inclusive scan via DPP (pure VALU) ----
template<int CTRL, int RM>
__device__ __forceinline__ float dpp_add(float v) {
    int t = __builtin_amdgcn_update_dpp(0, __float_as_int(v), CTRL, RM, 0xf, true);
    return v + __int_as_float(t);
}
__device__ __forceinline__ float wave_iscan(float v) {
    v = dpp_add<0x111, 0xf>(v);   // row_shr:1
    v = dpp_add<0x112, 0xf>(v);   // row_shr:2
    v = dpp_add<0x114, 0xf>(v);   // row_shr:4
    v = dpp_add<0x118, 0xf>(v);   // row_shr:8
    v = dpp_add<0x142, 0xa>(v);   // row_bcast:15 -> rows 1,3
    v = dpp_add<0x143, 0xc>(v);   // row_bcast:31 -> rows 2,3
    return v;
}

__device__ __forceinline__ void fma4(float4& acc, float c, const float4& v) {
    acc.x = fmaf(c, v.x, acc.x);
    acc.y = fmaf(c, v.y, acc.y);
    acc.z = fmaf(c, v.z, acc.z);
    acc.w = fmaf(c, v.w, acc.w);
}

// 256 threads = 4 waves; ONE path per block; grid = 2048 -> 7 blocks/CU (LDS),
// 28 waves/CU. Wave w handles t in [128w, 128w+128), thread owns t = 2tid, 2tid+1.
__global__ __launch_bounds__(256, 7) void path_kernel(
    const float* __restrict__ dz, const float* __restrict__ ws,
    float* __restrict__ out)
{
    __shared__ __align__(16) float planes[4 * PLANE]; // 8320 B, component-major fbm4
    __shared__ __align__(16) float wp[768];           // 3072 B: wp[j] = (j<256 ? 0 : w[j-256])
    __shared__ float chunk[64 * 41];                  // 10496 B   (total 21888 B)

    int tid = threadIdx.x;
    int lane = tid & 63;
    int wv = __builtin_amdgcn_readfirstlane(tid >> 6);
    int p = blockIdx.x;
    const float4* dzg = (const float4*)dz + (size_t)p * NS;

    for (int i = tid; i < 768; i += 256) wp[i] = (i < 256) ? 0.0f : ws[i - 256];
    __syncthreads();

    // ---- Phase B: fbm4[t] = sum_s w[t-s]*dz[s]; t = 2tid, 2tid+1.
    // dz[s] wave-uniform -> scalar loads; w via float2 LDS reads with register
    // reuse (low pair of group g == high pair of group g+1).
    {
        const float2* wpd = (const float2*)wp;
        int gmax = 32 * (wv + 1);                 // triangular skip per wave
        float4 a0 = make_float4(0.f, 0.f, 0.f, 0.f);
        float4 a1 = a0;
        float2 cr = wpd[tid + 128];               // = w[2tid], w[2tid+1]
        #pragma unroll 2
        for (int g = 0; g < gmax; ++g) {
            float4 d0 = dzg[4 * g + 0];           // uniform address
            float4 d1 = dzg[4 * g + 1];
            float4 d2 = dzg[4 * g + 2];
            float4 d3 = dzg[4 * g + 3];
            float2 A = wpd[tid - 2 * g + 126];
            float2 B = wpd[tid - 2 * g + 127];
            fma4(a0, cr.x, d0); fma4(a1, cr.y, d0);
            fma4(a0, B.y,  d1); fma4(a1, cr.x, d1);
            fma4(a0, B.x,  d2); fma4(a1, B.y,  d2);
            fma4(a0, A.y,  d3); fma4(a1, B.x,  d3);
            cr = A;                               // becomes next group's high pair
        }
        ((float2*)(planes + 0 * PLANE))[tid] = make_float2(a0.x, a1.x);
        ((float2*)(planes + 1 * PLANE))[tid] = make_float2(a0.y, a1.y);
        ((float2*)(planes + 2 * PLANE))[tid] = make_float2(a0.z, a1.z);
        ((float2*)(planes + 3 * PLANE))[tid] = make_float2(a0.w, a1.w);
    }

    float carry[10];
    #pragma unroll
    for (int j = 0; j < 10; ++j) carry[j] = 0.0f;

    float* outp = out + (size_t)p * (ROWS_OUT * NF);
    if (tid < NF) outp[tid] = ws[1024 + tid * 8 + 7];   // row 0 = F0

    __syncthreads();

    // ---- Phase C/D: lane = t within chunk; dF, DPP scan, transpose, store.
    const float* cwg = ws + NS;
    for (int cix = 0; cix < 8; ++cix) {
        int t = cix * 64 + lane;
        float cw = cwg[t];                        // coalesced global, L2-hot
        float fx = planes[t], fy = planes[PLANE + t];
        float fz = planes[2 * PLANE + t], fw = planes[3 * PLANE + t];
        float4 d = dzg[t];
        #pragma unroll
        for (int j = 0; j < 10; ++j) {
            int n = wv * 10 + j;                  // wave-uniform -> scalar loads
            const float* c = ws + 1024 + n * 8;
            float cC0 = c[0], cC1 = c[1], cC2 = c[2], q = c[3];
            float cA3 = c[4], ca = c[5], cm0 = c[6], f0 = c[7];
            float dotf = fx * cC0 + fy * cC1 + fz * cC2;
            float arg = fmaf(q, dotf, fmaf(cA3, fw, -ca * cw));
            float uv = __expf(arg);
            float dotc = d.x * cC0 + d.y * cC1 + d.z * cC2;
            float dF = uv * fmaf(cm0, uv, dotc);
            float v = wave_iscan(dF) + carry[j];
            carry[j] = __int_as_float(__builtin_amdgcn_readlane(__float_as_int(v), 63));
            chunk[lane * 41 + n] = v + f0;
        }
        __syncthreads();
        float* o = outp + NF + cix * (64 * NF);
        #pragma unroll
        for (int k = 0; k < 10; ++k) {
            int f = tid + k * 256;                // 2560 contiguous floats
            __builtin_nontemporal_store(chunk[f + f / 40], o + f);
        }
        __syncthreads();
    }
}

extern "C" void kernel_launch(void* const* d_in, const int* in_sizes, int n_in,
                              void* d_out, int out_size, void* d_ws, size_t ws_size,
                              hipStream_t stream) {
    const float* dz   = (const float*)d_in[0];
    const float* F0   = (const float*)d_in[1];
    const float* alph = (const float*)d_in[2];
    const float* rhos = (const float*)d_in[3];
    const float* nus  = (const float*)d_in[4];
    const float* tau  = (const float*)d_in[5];
    const float* L    = (const float*)d_in[6];
    const float* Lam  = (const float*)d_in[7];
    float* ws = (float*)d_ws;
    float* out = (float*)d_out;

    int n_paths = in_sizes[0] / (NS * 4);

    precomp_kernel<<<1, 512, 0, stream>>>(F0, alph, rhos, nus, tau, L, Lam, ws);
    path_kernel<<<n_paths, 256, 0, stream>>>(dz, ws, out);
}